// Round 13
// baseline (195.925 us; speedup 1.0000x reference)
//
#include <hip/hip_runtime.h>
#include <hip/hip_bf16.h>
#include <math.h>

// Soft-MoE forward. B=8, M=4096, D=512, E=64, P=1, H=2048.
// R13: R12 + complete nontemporal sweep — nt-loads on all read-once streams
// (x, xs_part, ys_part, logitsb@combine), nt-stores on cross-kernel
// intermediates (xs_part, h_part, ys_part). xnb stays cached (same-block reuse).

namespace {
constexpr int B = 8, M = 4096, D = 512, E = 64, H = 2048;
constexpr int NSD = 32;   // 128-row m-splits
constexpr int NQ1 = 8;    // g1 d-slabs
constexpr int NQ2 = 8;    // g2 k-slabs

constexpr size_t OFF_PHT  = 0;                                   // D*E bf16
constexpr size_t OFF_XNB  = OFF_PHT  + (size_t)D * E / 2;        // B*M*D bf16 (aliased by h_part)
constexpr size_t OFF_LOGB = OFF_XNB  + (size_t)B * M * D / 2;    // B*M*E bf16
constexpr size_t OFF_PMAX = OFF_LOGB + (size_t)B * M * E / 2;    // B*NSD*E f32
constexpr size_t OFF_PSUM = OFF_PMAX + (size_t)B * NSD * E;
constexpr size_t OFF_XSP  = OFF_PSUM + (size_t)B * NSD * E;      // NSD*B*E*D bf16 (aliased by ys_part)
constexpr size_t OFF_XSF  = OFF_XSP  + (size_t)NSD * B * E * D / 2; // E*D*B f32
constexpr size_t OFF_YST  = OFF_XSF  + (size_t)E * D * B;        // B*D*E bf16
constexpr size_t WS_FLOATS = OFF_YST + (size_t)B * D * E / 2;    // ~57 MB
} // namespace

typedef __attribute__((ext_vector_type(8))) short short8v;
typedef __attribute__((ext_vector_type(4))) float f32x4;
typedef __attribute__((ext_vector_type(4))) unsigned int u32x4;

static __device__ inline unsigned short f2bf(float f) {
  __hip_bfloat16 h = __float2bfloat16(f);
  return *reinterpret_cast<unsigned short*>(&h);
}
static __device__ inline float bf2f(unsigned short u) {
  unsigned int x = ((unsigned int)u) << 16;
  return __uint_as_float(x);
}
static __device__ inline short8v ld4w(const unsigned int* p, int a) {
  union { unsigned int u[4]; short8v v; } x;
  x.u[0] = p[a]; x.u[1] = p[a + 1]; x.u[2] = p[a + 2]; x.u[3] = p[a + 3];
  return x.v;
}
static __device__ inline f32x4 ldnt4(const float* p) {
  return __builtin_nontemporal_load((const f32x4*)p);
}
static __device__ inline u32x4 ldntu4(const unsigned short* p) {
  return __builtin_nontemporal_load((const u32x4*)p);
}
static __device__ inline unsigned int ldntu1(const unsigned short* p) {
  return __builtin_nontemporal_load((const unsigned int*)p);
}
static __device__ inline void stntu4(unsigned short* p, u32x4 v) {
  __builtin_nontemporal_store(v, (u32x4*)p);
}

// ---- K1: phT[e][d] = bf16(scale * l2norm(phi, axis=0)). grid 64, block 256 ----
__global__ __launch_bounds__(256) void k_phinorm(const float* __restrict__ phi,
                                                 const float* __restrict__ scale,
                                                 unsigned short* __restrict__ phT) {
  int e = blockIdx.x;
  int t = threadIdx.x;
  float v0 = phi[(size_t)t * E + e];
  float v1 = phi[(size_t)(t + 256) * E + e];
  __shared__ float red[256];
  red[t] = v0 * v0 + v1 * v1;
  __syncthreads();
  for (int s = 128; s; s >>= 1) {
    if (t < s) red[t] += red[t + s];
    __syncthreads();
  }
  float inv = scale[0] / fmaxf(sqrtf(red[0]), 1e-12f);
  phT[(size_t)e * D + t]       = f2bf(v0 * inv);
  phT[(size_t)e * D + t + 256] = f2bf(v1 * inv);
}

// ---- K2: fused rownorm + logits MFMA + stats + dispatch MFMA ----
// (nt-load on x; nt-store on xs_part repack; xnb stays cached.)
__global__ __launch_bounds__(256) void k_logdis(const float* __restrict__ x,
                                                const unsigned short* __restrict__ phT,
                                                unsigned short* __restrict__ xnb,
                                                unsigned short* __restrict__ logitsb,
                                                float* __restrict__ pmax,
                                                float* __restrict__ psum,
                                                unsigned short* __restrict__ xs_part) {
  __shared__ __align__(16) unsigned char pool[80896];
  unsigned short* phs = (unsigned short*)pool;            // [64 e][520 k]
  unsigned short* xA  = (unsigned short*)(pool + 66560);  // [128 m][56 k]
  unsigned int* weT = (unsigned int*)pool;                // [64 e][65 mp]
  unsigned int* xnT = (unsigned int*)(pool + 16640);      // [128 d][65 mp]
  unsigned short* rp = (unsigned short*)(pool + 49920);   // [64 e][136 d]
  __shared__ float invs[128];
  __shared__ float smax[4][64];
  __shared__ float bmax[64];
  int t = threadIdx.x;
  int lane = t & 63, w = t >> 6;
  int blk = blockIdx.x;
  int b = blk >> 5, ms = blk & 31;
  int rowbase = blk * 128;
  {
    int e = t >> 2, q0 = (t & 3) * 16;
#pragma unroll
    for (int q = 0; q < 16; q++)
      *(short8v*)&phs[e * 520 + (q0 + q) * 8] =
          *(const short8v*)&phT[(size_t)e * D + (q0 + q) * 8];
  }
  int srow = t >> 1;
  int kb = (t & 1) * 16;
  float ss = 0.f;
  f32x4 acc[2][4];
#pragma unroll
  for (int i = 0; i < 2; i++)
#pragma unroll
    for (int j = 0; j < 4; j++) acc[i][j] = (f32x4)(0.f);
  int kg = lane >> 4;
  int l15 = lane & 15;
  for (int ks = 0; ks < 16; ks++) {
    __syncthreads();
    const float* xp = x + (size_t)(rowbase + srow) * D + ks * 32 + kb;
#pragma unroll
    for (int q = 0; q < 4; q++) {
      f32x4 v = ldnt4(xp + q * 4);
      ss += v[0] * v[0] + v[1] * v[1] + v[2] * v[2] + v[3] * v[3];
      ushort4 u;
      u.x = f2bf(v[0]); u.y = f2bf(v[1]); u.z = f2bf(v[2]); u.w = f2bf(v[3]);
      *(ushort4*)&xA[srow * 56 + kb + q * 4] = u;
    }
    __syncthreads();
    {
      uint4 x0 = *(uint4*)&xA[srow * 56 + kb];
      uint4 x1 = *(uint4*)&xA[srow * 56 + kb + 8];
      size_t go = (size_t)(rowbase + srow) * D + ks * 32 + kb;
      *(uint4*)&xnb[go]     = x0;
      *(uint4*)&xnb[go + 8] = x1;
    }
    short8v a0 = *(short8v*)&xA[(w * 32 + l15) * 56 + kg * 8];
    short8v a1 = *(short8v*)&xA[(w * 32 + 16 + l15) * 56 + kg * 8];
    short8v b0 = *(short8v*)&phs[(l15)      * 520 + ks * 32 + kg * 8];
    short8v b1 = *(short8v*)&phs[(16 + l15) * 520 + ks * 32 + kg * 8];
    short8v b2 = *(short8v*)&phs[(32 + l15) * 520 + ks * 32 + kg * 8];
    short8v b3 = *(short8v*)&phs[(48 + l15) * 520 + ks * 32 + kg * 8];
    acc[0][0] = __builtin_amdgcn_mfma_f32_16x16x32_bf16(a0, b0, acc[0][0], 0, 0, 0);
    acc[0][1] = __builtin_amdgcn_mfma_f32_16x16x32_bf16(a0, b1, acc[0][1], 0, 0, 0);
    acc[0][2] = __builtin_amdgcn_mfma_f32_16x16x32_bf16(a0, b2, acc[0][2], 0, 0, 0);
    acc[0][3] = __builtin_amdgcn_mfma_f32_16x16x32_bf16(a0, b3, acc[0][3], 0, 0, 0);
    acc[1][0] = __builtin_amdgcn_mfma_f32_16x16x32_bf16(a1, b0, acc[1][0], 0, 0, 0);
    acc[1][1] = __builtin_amdgcn_mfma_f32_16x16x32_bf16(a1, b1, acc[1][1], 0, 0, 0);
    acc[1][2] = __builtin_amdgcn_mfma_f32_16x16x32_bf16(a1, b2, acc[1][2], 0, 0, 0);
    acc[1][3] = __builtin_amdgcn_mfma_f32_16x16x32_bf16(a1, b3, acc[1][3], 0, 0, 0);
  }
  ss += __shfl_xor(ss, 1, 64);
  float iv = 1.0f / fmaxf(sqrtf(ss), 1e-12f);
  if ((t & 1) == 0) invs[srow] = iv;
  __syncthreads();
  int rsub = kg * 4;
  float lm[4] = {-1e30f, -1e30f, -1e30f, -1e30f};
#pragma unroll
  for (int fi = 0; fi < 2; fi++)
#pragma unroll
    for (int r = 0; r < 4; r++) {
      int row = w * 32 + fi * 16 + rsub + r;
      float ivr = invs[row];
#pragma unroll
      for (int eg = 0; eg < 4; eg++) {
        float v = acc[fi][eg][r] * ivr;
        logitsb[(size_t)(rowbase + row) * E + eg * 16 + l15] = f2bf(v);
        lm[eg] = fmaxf(lm[eg], v);
      }
    }
#pragma unroll
  for (int eg = 0; eg < 4; eg++) {
    lm[eg] = fmaxf(lm[eg], __shfl_xor(lm[eg], 16, 64));
    lm[eg] = fmaxf(lm[eg], __shfl_xor(lm[eg], 32, 64));
  }
  if (lane < 16)
#pragma unroll
    for (int eg = 0; eg < 4; eg++) smax[w][eg * 16 + lane] = lm[eg];
  __syncthreads();
  if (t < 64)
    bmax[t] = fmaxf(fmaxf(smax[0][t], smax[1][t]), fmaxf(smax[2][t], smax[3][t]));
  __syncthreads();
  float ps[4] = {0.f, 0.f, 0.f, 0.f};
#pragma unroll
  for (int fi = 0; fi < 2; fi++)
#pragma unroll
    for (int r2 = 0; r2 < 2; r2++) {
      int rowA = w * 32 + fi * 16 + rsub + 2 * r2;
      float iv0 = invs[rowA], iv1 = invs[rowA + 1];
#pragma unroll
      for (int eg = 0; eg < 4; eg++) {
        float bm = bmax[eg * 16 + l15];
        float p0 = __expf(acc[fi][eg][2 * r2]     * iv0 - bm);
        float p1 = __expf(acc[fi][eg][2 * r2 + 1] * iv1 - bm);
        ps[eg] += p0 + p1;
        weT[(eg * 16 + l15) * 65 + (w * 16 + fi * 8 + (rsub >> 1) + r2)] =
            (unsigned int)f2bf(p0 * iv0) | ((unsigned int)f2bf(p1 * iv1) << 16);
      }
    }
#pragma unroll
  for (int eg = 0; eg < 4; eg++) {
    ps[eg] += __shfl_xor(ps[eg], 16, 64);
    ps[eg] += __shfl_xor(ps[eg], 32, 64);
  }
  __syncthreads();
  if (lane < 16)
#pragma unroll
    for (int eg = 0; eg < 4; eg++) smax[w][eg * 16 + lane] = ps[eg];
  __syncthreads();
  if (t < 64) {
    pmax[(size_t)blk * 64 + t] = bmax[t];
    psum[(size_t)blk * 64 + t] =
        smax[0][t] + smax[1][t] + smax[2][t] + smax[3][t];
  }
  unsigned short* outp = xs_part + ((size_t)ms * B + b) * E * D;
  for (int dc = 0; dc < 4; dc++) {
    __syncthreads();
#pragma unroll
    for (int i = 0; i < 16; i++) {
      int flat = i * 256 + t;
      int mp = flat >> 6, d2 = flat & 63;
      size_t rbase = (size_t)(rowbase + 2 * mp) * D + dc * 128 + d2 * 2;
      unsigned int ua = *(const unsigned int*)&xnb[rbase];
      unsigned int ub = *(const unsigned int*)&xnb[rbase + D];
      xnT[(2 * d2 + 0) * 65 + mp] = (ua & 0xffffu) | ((ub & 0xffffu) << 16);
      xnT[(2 * d2 + 1) * 65 + mp] = (ua >> 16) | (ub & 0xffff0000u);
    }
    __syncthreads();
    f32x4 ac3[4][2];
#pragma unroll
    for (int i = 0; i < 4; i++) { ac3[i][0] = (f32x4)(0.f); ac3[i][1] = (f32x4)(0.f); }
#pragma unroll
    for (int ks2 = 0; ks2 < 4; ks2++) {
      short8v afr[4];
#pragma unroll
      for (int et = 0; et < 4; et++)
        afr[et] = ld4w(weT, (et * 16 + l15) * 65 + ks2 * 16 + kg * 4);
#pragma unroll
      for (int dtl = 0; dtl < 2; dtl++) {
        short8v bfr = ld4w(xnT, (w * 32 + dtl * 16 + l15) * 65 + ks2 * 16 + kg * 4);
#pragma unroll
        for (int et = 0; et < 4; et++)
          ac3[et][dtl] = __builtin_amdgcn_mfma_f32_16x16x32_bf16(afr[et], bfr, ac3[et][dtl], 0, 0, 0);
      }
    }
#pragma unroll
    for (int et = 0; et < 4; et++)
#pragma unroll
      for (int dtl = 0; dtl < 2; dtl++)
#pragma unroll
        for (int r = 0; r < 4; r++) {
          int e = et * 16 + rsub + r;
          int d = w * 32 + dtl * 16 + l15;
          rp[e * 136 + d] = f2bf(ac3[et][dtl][r]);
        }
    __syncthreads();
    {
      int g = t >> 4, dch = t & 15;
#pragma unroll
      for (int pp = 0; pp < 4; pp++) {
        int el = pp * 16 + g;
        u32x4 v = *(u32x4*)&rp[el * 136 + dch * 8];
        stntu4(outp + (size_t)el * D + dc * 128 + dch * 8, v);
      }
    }
  }
}

// ---- K3: xs_f[e][d][b] = (sum_ms xs_part * exp(pmax-gm)) / dsum. grid B*E=512 ----
__global__ __launch_bounds__(256) void k_xsred(const unsigned short* __restrict__ xs_part,
                                               const float* __restrict__ pmax,
                                               const float* __restrict__ psum,
                                               float* __restrict__ xs_f) {
  int blk = blockIdx.x;
  int b = blk >> 6, e = blk & 63;
  int t = threadIdx.x;
  float gm = -1e30f;
  for (int s = 0; s < NSD; s++)
    gm = fmaxf(gm, pmax[((size_t)(b * NSD + s)) * 64 + e]);
  float gs = 0.f;
  for (int s = 0; s < NSD; s++)
    gs += psum[((size_t)(b * NSD + s)) * 64 + e] *
          __expf(pmax[((size_t)(b * NSD + s)) * 64 + e] - gm);
  float inv = 1.0f / gs;
  size_t base = (((size_t)b * E + e) * D) / 2 + t;
  size_t slab = ((size_t)B * E * D) / 2;
  float a0 = 0.f, a1 = 0.f;
  const unsigned short* pp = xs_part;
  for (int s = 0; s < NSD; s++) {
    float f = __expf(pmax[((size_t)(b * NSD + s)) * 64 + e] - gm);
    unsigned int v = ldntu1(pp + 2 * ((size_t)s * slab + base));
    a0 += f * bf2f((unsigned short)(v & 0xffff));
    a1 += f * bf2f((unsigned short)(v >> 16));
  }
  int d = t * 2;
  xs_f[((size_t)e * D + d) * B + b]     = a0 * inv;
  xs_f[((size_t)e * D + d + 1) * B + b] = a1 * inv;
}

// ---- K4: gemm1, fill-shaped + nt. grid 512 = (e, dq 0..7), block 256 ----
__global__ __launch_bounds__(256) void k_g1(const float* __restrict__ w1,
                                            const float* __restrict__ xs_f,
                                            unsigned short* __restrict__ h_part) {
  __shared__ float xsm[64 * 8];  // 2 KB
  int blk = blockIdx.x;
  int dq = blk & 7, e = blk >> 3;
  int t = threadIdx.x;
  if (t < 128)
    ((float4*)xsm)[t] = ((const float4*)(xs_f + ((size_t)e * D + dq * 64) * B))[t];
  __syncthreads();
  const float* wp = w1 + ((size_t)e * D + dq * 64) * H + t * 8;
  float acc[8][8];
#pragma unroll
  for (int i = 0; i < 8; i++)
#pragma unroll
    for (int j = 0; j < 8; j++) acc[i][j] = 0.f;
#pragma unroll 4
  for (int r = 0; r < 64; r++) {
    f32x4 wa = ldnt4(wp + (size_t)r * H);
    f32x4 wb = ldnt4(wp + (size_t)r * H + 4);
    float x8[8];
    *(float4*)&x8[0] = *(float4*)&xsm[r * 8];
    *(float4*)&x8[4] = *(float4*)&xsm[r * 8 + 4];
#pragma unroll
    for (int bb = 0; bb < 8; bb++) {
      acc[0][bb] += wa[0] * x8[bb]; acc[1][bb] += wa[1] * x8[bb];
      acc[2][bb] += wa[2] * x8[bb]; acc[3][bb] += wa[3] * x8[bb];
      acc[4][bb] += wb[0] * x8[bb]; acc[5][bb] += wb[1] * x8[bb];
      acc[6][bb] += wb[2] * x8[bb]; acc[7][bb] += wb[3] * x8[bb];
    }
  }
  unsigned short* op = h_part + (((size_t)dq * E + e) * H + t * 8) * B;
#pragma unroll
  for (int i = 0; i < 8; i++) {
    unsigned short us[8];
#pragma unroll
    for (int j = 0; j < 8; j++) us[j] = f2bf(acc[i][j]);
    stntu4(op + (size_t)i * 8, *(u32x4*)us);
  }
}

// ---- K5: gemm2, fill-shaped + gelu fold + nt + float4 kk-split.
// grid 512 = (e, kq 0..7), block 256.
__global__ __launch_bounds__(256) void k_g2(const float* __restrict__ w2,
                                            const float* __restrict__ b1,
                                            const unsigned short* __restrict__ h_part,
                                            unsigned short* __restrict__ ys_part) {
  __shared__ float hsm[256 * 8];    // 8 KB
  __shared__ float cbuf[128 * 33];  // 16.9 KB
  int blk = blockIdx.x;
  int kq = blk & 7, e = blk >> 3;
  int t = threadIdx.x;
  {
    int j = kq * 256 + t;
    const unsigned short* base = h_part + ((size_t)e * H + j) * B;
    float a[8] = {0.f, 0.f, 0.f, 0.f, 0.f, 0.f, 0.f, 0.f};
#pragma unroll
    for (int dq = 0; dq < NQ1; dq++) {
      u32x4 v = ldntu4(base + (size_t)dq * E * H * B);
      const unsigned short* u = (const unsigned short*)&v;
#pragma unroll
      for (int bb = 0; bb < 8; bb++) a[bb] += bf2f(u[bb]);
    }
    float bias = b1[(size_t)e * H + j];
#pragma unroll
    for (int bb = 0; bb < 8; bb++) {
      float vv = a[bb] + bias;
      hsm[t * 8 + bb] = 0.5f * vv * (1.0f + erff(vv * 0.70710678118654752f));
    }
  }
  __syncthreads();
  int kk = t >> 7, dq2 = t & 127;
  int d0 = dq2 * 4;
  const float* wp = w2 + ((size_t)e * H + kq * 256 + kk * 128) * D + d0;
  const float* hb = hsm + kk * 128 * 8;
  float acc[4][8];
#pragma unroll
  for (int i = 0; i < 4; i++)
#pragma unroll
    for (int j = 0; j < 8; j++) acc[i][j] = 0.f;
#pragma unroll 4
  for (int r = 0; r < 128; r++) {
    f32x4 w = ldnt4(wp + (size_t)r * D);
    float h8[8];
    *(float4*)&h8[0] = *(float4*)&hb[r * 8];
    *(float4*)&h8[4] = *(float4*)&hb[r * 8 + 4];
#pragma unroll
    for (int bb = 0; bb < 8; bb++) {
      acc[0][bb] += w[0] * h8[bb]; acc[1][bb] += w[1] * h8[bb];
      acc[2][bb] += w[2] * h8[bb]; acc[3][bb] += w[3] * h8[bb];
    }
  }
  if (kk) {
    float* cb = &cbuf[dq2 * 33];
#pragma unroll
    for (int i = 0; i < 4; i++) {
      *(float4*)(cb + i * 8)     = *(float4*)&acc[i][0];
      *(float4*)(cb + i * 8 + 4) = *(float4*)&acc[i][4];
    }
  }
  __syncthreads();
  if (!kk) {
    const float* cb = &cbuf[dq2 * 33];
    unsigned short* op = ys_part + (((size_t)kq * E + e) * D + d0) * B;
#pragma unroll
    for (int i = 0; i < 4; i++) {
      unsigned short us[8];
#pragma unroll
      for (int j = 0; j < 8; j++)
        us[j] = f2bf(acc[i][j] + cb[i * 8 + j]);
      stntu4(op + (size_t)i * 8, *(u32x4*)us);
    }
  }
}

// ---- K6: ysT[b][d][e] = bf16(sum_kq ys_part + b2). grid E*4=256 ----
__global__ __launch_bounds__(256) void k_ysred(const unsigned short* __restrict__ ys_part,
                                               const float* __restrict__ b2,
                                               unsigned short* __restrict__ ysT) {
  int e = blockIdx.x >> 2, kqq = blockIdx.x & 3;
  int t = threadIdx.x;
  int i4 = kqq * 256 + t;
  float a[4] = {0.f, 0.f, 0.f, 0.f};
  for (int ks = 0; ks < NQ2; ks++) {
    const unsigned short* q = ys_part + ((size_t)ks * E + e) * D * B;
    unsigned long long vv = __builtin_nontemporal_load(
        (const unsigned long long*)(q + (size_t)i4 * 4));
    a[0] += bf2f((unsigned short)(vv & 0xffff));
    a[1] += bf2f((unsigned short)((vv >> 16) & 0xffff));
    a[2] += bf2f((unsigned short)((vv >> 32) & 0xffff));
    a[3] += bf2f((unsigned short)(vv >> 48));
  }
  int d = i4 >> 1, bh = (i4 & 1) * 4;
  float bias = b2[e * D + d];
#pragma unroll
  for (int j = 0; j < 4; j++)
    ysT[((size_t)(bh + j) * D + d) * E + e] = f2bf(a[j] + bias);
}

// ---- K7: combine via MFMA (nt on logitsb). grid B*64*2=1024 ----
__global__ __launch_bounds__(256) void k_combine(const unsigned short* __restrict__ logitsb,
                                                 const unsigned short* __restrict__ ysT,
                                                 float* __restrict__ y) {
  __shared__ unsigned int yss[256 * 34];
  __shared__ unsigned int cb[64 * 34];
  __shared__ float red[64][4];
  __shared__ float gmx[64], gsm[64];
  int t = threadIdx.x;
  int lane = t & 63, w = t >> 6;
  int blk = blockIdx.x;
  int dg = blk & 1, mb = (blk >> 1) & 63, b = blk >> 7;
  int m0 = mb * 64;
  {
    int dloc = t >> 3, ch = t & 7;
    const unsigned short* src = ysT + ((size_t)b * D + dg * 256) * E;
#pragma unroll
    for (int p = 0; p < 8; p++) {
      int d = p * 32 + dloc;
      const unsigned int* sp = (const unsigned int*)&src[(size_t)d * E + ch * 8];
      unsigned int* dst = &yss[d * 34 + ch * 4];
      dst[0] = sp[0]; dst[1] = sp[1]; dst[2] = sp[2]; dst[3] = sp[3];
    }
  }
  int row = t >> 2, sub = t & 3;
  float r16[16];
  {
    const unsigned short* Lr = logitsb + ((size_t)(b * M + m0 + row)) * E + sub * 16;
    u32x4 v0 = ldntu4(Lr);
    u32x4 v1 = ldntu4(Lr + 8);
    const unsigned short* u0 = (const unsigned short*)&v0;
    const unsigned short* u1 = (const unsigned short*)&v1;
#pragma unroll
    for (int k = 0; k < 8; k++) {
      r16[k]     = bf2f(u0[k]);
      r16[8 + k] = bf2f(u1[k]);
    }
  }
  float lm = -1e30f;
#pragma unroll
  for (int k = 0; k < 16; k++) lm = fmaxf(lm, r16[k]);
  red[row][sub] = lm;
  __syncthreads();
  if (sub == 0)
    gmx[row] = fmaxf(fmaxf(red[row][0], red[row][1]), fmaxf(red[row][2], red[row][3]));
  __syncthreads();
  float g = gmx[row];
  float ls = 0.f;
#pragma unroll
  for (int k = 0; k < 16; k++) {
    r16[k] = __expf(r16[k] - g);
    ls += r16[k];
  }
  red[row][sub] = ls;
  __syncthreads();
  if (sub == 0)
    gsm[row] = 1.0f / (red[row][0] + red[row][1] + red[row][2] + red[row][3]);
  __syncthreads();
  float is = gsm[row];
  {
    unsigned int us[8];
#pragma unroll
    for (int k = 0; k < 8; k++)
      us[k] = (unsigned int)f2bf(r16[2 * k] * is) |
              ((unsigned int)f2bf(r16[2 * k + 1] * is) << 16);
    unsigned int* dst = &cb[row * 34 + sub * 8];
#pragma unroll
    for (int k = 0; k < 8; k++) dst[k] = us[k];
  }
  __syncthreads();
  int kg = lane >> 4, l15 = lane & 15;
  f32x4 acc[4][4];
#pragma unroll
  for (int i = 0; i < 4; i++)
#pragma unroll
    for (int j = 0; j < 4; j++) acc[i][j] = (f32x4)(0.f);
#pragma unroll
  for (int ks = 0; ks < 2; ks++) {
    short8v afr[4];
#pragma unroll
    for (int mt = 0; mt < 4; mt++)
      afr[mt] = ld4w(cb, (mt * 16 + l15) * 34 + ks * 16 + kg * 4);
#pragma unroll
    for (int dt = 0; dt < 4; dt++) {
      short8v bfr = ld4w(yss, (w * 64 + dt * 16 + l15) * 34 + ks * 16 + kg * 4);
#pragma unroll
      for (int mt = 0; mt < 4; mt++)
        acc[mt][dt] = __builtin_amdgcn_mfma_f32_16x16x32_bf16(afr[mt], bfr, acc[mt][dt], 0, 0, 0);
    }
  }
#pragma unroll
  for (int mt = 0; mt < 4; mt++)
#pragma unroll
    for (int dt = 0; dt < 4; dt++)
#pragma unroll
      for (int r = 0; r < 4; r++) {
        int m = mt * 16 + kg * 4 + r;
        int d = dg * 256 + w * 64 + dt * 16 + l15;
        y[((size_t)(b * M + m0 + m)) * D + d] = acc[mt][dt][r];
      }
}

extern "C" void kernel_launch(void* const* d_in, const int* in_sizes, int n_in,
                              void* d_out, int out_size, void* d_ws, size_t ws_size,
                              hipStream_t stream) {
  const float* x     = (const float*)d_in[0];
  const float* phi   = (const float*)d_in[1];
  const float* scale = (const float*)d_in[2];
  const float* w1    = (const float*)d_in[3];
  const float* b1    = (const float*)d_in[4];
  const float* w2    = (const float*)d_in[5];
  const float* b2    = (const float*)d_in[6];
  float* y = (float*)d_out;
  float* ws = (float*)d_ws;
  (void)in_sizes; (void)n_in; (void)out_size; (void)ws_size;

  unsigned short* phT     = (unsigned short*)(ws + OFF_PHT);
  unsigned short* xnb     = (unsigned short*)(ws + OFF_XNB);
  unsigned short* logitsb = (unsigned short*)(ws + OFF_LOGB);
  float* pmax    = ws + OFF_PMAX;
  float* psum    = ws + OFF_PSUM;
  unsigned short* xs_part = (unsigned short*)(ws + OFF_XSP);
  float* xs_f    = ws + OFF_XSF;
  unsigned short* ysT     = (unsigned short*)(ws + OFF_YST);
  unsigned short* h_part  = xnb;      // alias (lifetimes disjoint)
  unsigned short* ys_part = xs_part;  // alias (lifetimes disjoint)

  k_phinorm<<<E, 256, 0, stream>>>(phi, scale, phT);
  k_logdis<<<B * NSD, 256, 0, stream>>>(x, phT, xnb, logitsb, pmax, psum, xs_part);
  k_xsred<<<B * E, 256, 0, stream>>>(xs_part, pmax, psum, xs_f);
  k_g1<<<E * NQ1, 256, 0, stream>>>(w1, xs_f, h_part);
  k_g2<<<E * NQ2, 256, 0, stream>>>(w2, b1, h_part, ys_part);
  k_ysred<<<E * 4, 256, 0, stream>>>(ys_part, b2, ysT);
  k_combine<<<B * 64 * 2, 256, 0, stream>>>(logitsb, ysT, y);
}

// Round 14
// 177.899 us; speedup vs baseline: 1.1013x; 1.1013x over previous
//
#include <hip/hip_runtime.h>
#include <hip/hip_bf16.h>
#include <math.h>

// Soft-MoE forward. B=8, M=4096, D=512, E=64, P=1, H=2048.
// R14: revert to R12 (nt only on read-once weight streams + h_part loads;
// NORMAL stores on all intermediates so consumers hit L3), plus nt-load on x.

namespace {
constexpr int B = 8, M = 4096, D = 512, E = 64, H = 2048;
constexpr int NSD = 32;   // 128-row m-splits
constexpr int NQ1 = 8;    // g1 d-slabs
constexpr int NQ2 = 8;    // g2 k-slabs

constexpr size_t OFF_PHT  = 0;                                   // D*E bf16
constexpr size_t OFF_XNB  = OFF_PHT  + (size_t)D * E / 2;        // B*M*D bf16 (aliased by h_part)
constexpr size_t OFF_LOGB = OFF_XNB  + (size_t)B * M * D / 2;    // B*M*E bf16
constexpr size_t OFF_PMAX = OFF_LOGB + (size_t)B * M * E / 2;    // B*NSD*E f32
constexpr size_t OFF_PSUM = OFF_PMAX + (size_t)B * NSD * E;
constexpr size_t OFF_XSP  = OFF_PSUM + (size_t)B * NSD * E;      // NSD*B*E*D bf16 (aliased by ys_part)
constexpr size_t OFF_XSF  = OFF_XSP  + (size_t)NSD * B * E * D / 2; // E*D*B f32
constexpr size_t OFF_YST  = OFF_XSF  + (size_t)E * D * B;        // B*D*E bf16
constexpr size_t WS_FLOATS = OFF_YST + (size_t)B * D * E / 2;    // ~57 MB
} // namespace

typedef __attribute__((ext_vector_type(8))) short short8v;
typedef __attribute__((ext_vector_type(4))) float f32x4;
typedef __attribute__((ext_vector_type(4))) unsigned int u32x4;

static __device__ inline unsigned short f2bf(float f) {
  __hip_bfloat16 h = __float2bfloat16(f);
  return *reinterpret_cast<unsigned short*>(&h);
}
static __device__ inline float bf2f(unsigned short u) {
  unsigned int x = ((unsigned int)u) << 16;
  return __uint_as_float(x);
}
static __device__ inline short8v ld4w(const unsigned int* p, int a) {
  union { unsigned int u[4]; short8v v; } x;
  x.u[0] = p[a]; x.u[1] = p[a + 1]; x.u[2] = p[a + 2]; x.u[3] = p[a + 3];
  return x.v;
}
static __device__ inline f32x4 ldnt4(const float* p) {
  return __builtin_nontemporal_load((const f32x4*)p);
}
static __device__ inline u32x4 ldntu4(const unsigned short* p) {
  return __builtin_nontemporal_load((const u32x4*)p);
}

// ---- K1: phT[e][d] = bf16(scale * l2norm(phi, axis=0)). grid 64, block 256 ----
__global__ __launch_bounds__(256) void k_phinorm(const float* __restrict__ phi,
                                                 const float* __restrict__ scale,
                                                 unsigned short* __restrict__ phT) {
  int e = blockIdx.x;
  int t = threadIdx.x;
  float v0 = phi[(size_t)t * E + e];
  float v1 = phi[(size_t)(t + 256) * E + e];
  __shared__ float red[256];
  red[t] = v0 * v0 + v1 * v1;
  __syncthreads();
  for (int s = 128; s; s >>= 1) {
    if (t < s) red[t] += red[t + s];
    __syncthreads();
  }
  float inv = scale[0] / fmaxf(sqrtf(red[0]), 1e-12f);
  phT[(size_t)e * D + t]       = f2bf(v0 * inv);
  phT[(size_t)e * D + t + 256] = f2bf(v1 * inv);
}

// ---- K2: fused rownorm + logits MFMA + stats + dispatch MFMA ----
// (nt-load on x only; all stores normal.)
__global__ __launch_bounds__(256) void k_logdis(const float* __restrict__ x,
                                                const unsigned short* __restrict__ phT,
                                                unsigned short* __restrict__ xnb,
                                                unsigned short* __restrict__ logitsb,
                                                float* __restrict__ pmax,
                                                float* __restrict__ psum,
                                                unsigned short* __restrict__ xs_part) {
  __shared__ __align__(16) unsigned char pool[80896];
  unsigned short* phs = (unsigned short*)pool;            // [64 e][520 k]
  unsigned short* xA  = (unsigned short*)(pool + 66560);  // [128 m][56 k]
  unsigned int* weT = (unsigned int*)pool;                // [64 e][65 mp]
  unsigned int* xnT = (unsigned int*)(pool + 16640);      // [128 d][65 mp]
  unsigned short* rp = (unsigned short*)(pool + 49920);   // [64 e][136 d]
  __shared__ float invs[128];
  __shared__ float smax[4][64];
  __shared__ float bmax[64];
  int t = threadIdx.x;
  int lane = t & 63, w = t >> 6;
  int blk = blockIdx.x;
  int b = blk >> 5, ms = blk & 31;
  int rowbase = blk * 128;
  {
    int e = t >> 2, q0 = (t & 3) * 16;
#pragma unroll
    for (int q = 0; q < 16; q++)
      *(short8v*)&phs[e * 520 + (q0 + q) * 8] =
          *(const short8v*)&phT[(size_t)e * D + (q0 + q) * 8];
  }
  int srow = t >> 1;
  int kb = (t & 1) * 16;
  float ss = 0.f;
  f32x4 acc[2][4];
#pragma unroll
  for (int i = 0; i < 2; i++)
#pragma unroll
    for (int j = 0; j < 4; j++) acc[i][j] = (f32x4)(0.f);
  int kg = lane >> 4;
  int l15 = lane & 15;
  for (int ks = 0; ks < 16; ks++) {
    __syncthreads();
    const float* xp = x + (size_t)(rowbase + srow) * D + ks * 32 + kb;
#pragma unroll
    for (int q = 0; q < 4; q++) {
      f32x4 v = ldnt4(xp + q * 4);
      ss += v[0] * v[0] + v[1] * v[1] + v[2] * v[2] + v[3] * v[3];
      ushort4 u;
      u.x = f2bf(v[0]); u.y = f2bf(v[1]); u.z = f2bf(v[2]); u.w = f2bf(v[3]);
      *(ushort4*)&xA[srow * 56 + kb + q * 4] = u;
    }
    __syncthreads();
    {
      uint4 x0 = *(uint4*)&xA[srow * 56 + kb];
      uint4 x1 = *(uint4*)&xA[srow * 56 + kb + 8];
      size_t go = (size_t)(rowbase + srow) * D + ks * 32 + kb;
      *(uint4*)&xnb[go]     = x0;
      *(uint4*)&xnb[go + 8] = x1;
    }
    short8v a0 = *(short8v*)&xA[(w * 32 + l15) * 56 + kg * 8];
    short8v a1 = *(short8v*)&xA[(w * 32 + 16 + l15) * 56 + kg * 8];
    short8v b0 = *(short8v*)&phs[(l15)      * 520 + ks * 32 + kg * 8];
    short8v b1 = *(short8v*)&phs[(16 + l15) * 520 + ks * 32 + kg * 8];
    short8v b2 = *(short8v*)&phs[(32 + l15) * 520 + ks * 32 + kg * 8];
    short8v b3 = *(short8v*)&phs[(48 + l15) * 520 + ks * 32 + kg * 8];
    acc[0][0] = __builtin_amdgcn_mfma_f32_16x16x32_bf16(a0, b0, acc[0][0], 0, 0, 0);
    acc[0][1] = __builtin_amdgcn_mfma_f32_16x16x32_bf16(a0, b1, acc[0][1], 0, 0, 0);
    acc[0][2] = __builtin_amdgcn_mfma_f32_16x16x32_bf16(a0, b2, acc[0][2], 0, 0, 0);
    acc[0][3] = __builtin_amdgcn_mfma_f32_16x16x32_bf16(a0, b3, acc[0][3], 0, 0, 0);
    acc[1][0] = __builtin_amdgcn_mfma_f32_16x16x32_bf16(a1, b0, acc[1][0], 0, 0, 0);
    acc[1][1] = __builtin_amdgcn_mfma_f32_16x16x32_bf16(a1, b1, acc[1][1], 0, 0, 0);
    acc[1][2] = __builtin_amdgcn_mfma_f32_16x16x32_bf16(a1, b2, acc[1][2], 0, 0, 0);
    acc[1][3] = __builtin_amdgcn_mfma_f32_16x16x32_bf16(a1, b3, acc[1][3], 0, 0, 0);
  }
  ss += __shfl_xor(ss, 1, 64);
  float iv = 1.0f / fmaxf(sqrtf(ss), 1e-12f);
  if ((t & 1) == 0) invs[srow] = iv;
  __syncthreads();
  int rsub = kg * 4;
  float lm[4] = {-1e30f, -1e30f, -1e30f, -1e30f};
#pragma unroll
  for (int fi = 0; fi < 2; fi++)
#pragma unroll
    for (int r = 0; r < 4; r++) {
      int row = w * 32 + fi * 16 + rsub + r;
      float ivr = invs[row];
#pragma unroll
      for (int eg = 0; eg < 4; eg++) {
        float v = acc[fi][eg][r] * ivr;
        logitsb[(size_t)(rowbase + row) * E + eg * 16 + l15] = f2bf(v);
        lm[eg] = fmaxf(lm[eg], v);
      }
    }
#pragma unroll
  for (int eg = 0; eg < 4; eg++) {
    lm[eg] = fmaxf(lm[eg], __shfl_xor(lm[eg], 16, 64));
    lm[eg] = fmaxf(lm[eg], __shfl_xor(lm[eg], 32, 64));
  }
  if (lane < 16)
#pragma unroll
    for (int eg = 0; eg < 4; eg++) smax[w][eg * 16 + lane] = lm[eg];
  __syncthreads();
  if (t < 64)
    bmax[t] = fmaxf(fmaxf(smax[0][t], smax[1][t]), fmaxf(smax[2][t], smax[3][t]));
  __syncthreads();
  float ps[4] = {0.f, 0.f, 0.f, 0.f};
#pragma unroll
  for (int fi = 0; fi < 2; fi++)
#pragma unroll
    for (int r2 = 0; r2 < 2; r2++) {
      int rowA = w * 32 + fi * 16 + rsub + 2 * r2;
      float iv0 = invs[rowA], iv1 = invs[rowA + 1];
#pragma unroll
      for (int eg = 0; eg < 4; eg++) {
        float bm = bmax[eg * 16 + l15];
        float p0 = __expf(acc[fi][eg][2 * r2]     * iv0 - bm);
        float p1 = __expf(acc[fi][eg][2 * r2 + 1] * iv1 - bm);
        ps[eg] += p0 + p1;
        weT[(eg * 16 + l15) * 65 + (w * 16 + fi * 8 + (rsub >> 1) + r2)] =
            (unsigned int)f2bf(p0 * iv0) | ((unsigned int)f2bf(p1 * iv1) << 16);
      }
    }
#pragma unroll
  for (int eg = 0; eg < 4; eg++) {
    ps[eg] += __shfl_xor(ps[eg], 16, 64);
    ps[eg] += __shfl_xor(ps[eg], 32, 64);
  }
  __syncthreads();
  if (lane < 16)
#pragma unroll
    for (int eg = 0; eg < 4; eg++) smax[w][eg * 16 + lane] = ps[eg];
  __syncthreads();
  if (t < 64) {
    pmax[(size_t)blk * 64 + t] = bmax[t];
    psum[(size_t)blk * 64 + t] =
        smax[0][t] + smax[1][t] + smax[2][t] + smax[3][t];
  }
  unsigned short* outp = xs_part + ((size_t)ms * B + b) * E * D;
  for (int dc = 0; dc < 4; dc++) {
    __syncthreads();
#pragma unroll
    for (int i = 0; i < 16; i++) {
      int flat = i * 256 + t;
      int mp = flat >> 6, d2 = flat & 63;
      size_t rbase = (size_t)(rowbase + 2 * mp) * D + dc * 128 + d2 * 2;
      unsigned int ua = *(const unsigned int*)&xnb[rbase];
      unsigned int ub = *(const unsigned int*)&xnb[rbase + D];
      xnT[(2 * d2 + 0) * 65 + mp] = (ua & 0xffffu) | ((ub & 0xffffu) << 16);
      xnT[(2 * d2 + 1) * 65 + mp] = (ua >> 16) | (ub & 0xffff0000u);
    }
    __syncthreads();
    f32x4 ac3[4][2];
#pragma unroll
    for (int i = 0; i < 4; i++) { ac3[i][0] = (f32x4)(0.f); ac3[i][1] = (f32x4)(0.f); }
#pragma unroll
    for (int ks2 = 0; ks2 < 4; ks2++) {
      short8v afr[4];
#pragma unroll
      for (int et = 0; et < 4; et++)
        afr[et] = ld4w(weT, (et * 16 + l15) * 65 + ks2 * 16 + kg * 4);
#pragma unroll
      for (int dtl = 0; dtl < 2; dtl++) {
        short8v bfr = ld4w(xnT, (w * 32 + dtl * 16 + l15) * 65 + ks2 * 16 + kg * 4);
#pragma unroll
        for (int et = 0; et < 4; et++)
          ac3[et][dtl] = __builtin_amdgcn_mfma_f32_16x16x32_bf16(afr[et], bfr, ac3[et][dtl], 0, 0, 0);
      }
    }
#pragma unroll
    for (int et = 0; et < 4; et++)
#pragma unroll
      for (int dtl = 0; dtl < 2; dtl++)
#pragma unroll
        for (int r = 0; r < 4; r++) {
          int e = et * 16 + rsub + r;
          int d = w * 32 + dtl * 16 + l15;
          rp[e * 136 + d] = f2bf(ac3[et][dtl][r]);
        }
    __syncthreads();
    {
      int g = t >> 4, dch = t & 15;
#pragma unroll
      for (int pp = 0; pp < 4; pp++) {
        int el = pp * 16 + g;
        uint4 v = *(uint4*)&rp[el * 136 + dch * 8];
        *(uint4*)(outp + (size_t)el * D + dc * 128 + dch * 8) = v;
      }
    }
  }
}

// ---- K3: xs_f[e][d][b] = (sum_ms xs_part * exp(pmax-gm)) / dsum. grid B*E=512 ----
__global__ __launch_bounds__(256) void k_xsred(const unsigned short* __restrict__ xs_part,
                                               const float* __restrict__ pmax,
                                               const float* __restrict__ psum,
                                               float* __restrict__ xs_f) {
  int blk = blockIdx.x;
  int b = blk >> 6, e = blk & 63;
  int t = threadIdx.x;
  float gm = -1e30f;
  for (int s = 0; s < NSD; s++)
    gm = fmaxf(gm, pmax[((size_t)(b * NSD + s)) * 64 + e]);
  float gs = 0.f;
  for (int s = 0; s < NSD; s++)
    gs += psum[((size_t)(b * NSD + s)) * 64 + e] *
          __expf(pmax[((size_t)(b * NSD + s)) * 64 + e] - gm);
  float inv = 1.0f / gs;
  size_t base = (((size_t)b * E + e) * D) / 2 + t;
  size_t slab = ((size_t)B * E * D) / 2;
  float a0 = 0.f, a1 = 0.f;
  const unsigned int* pp = (const unsigned int*)xs_part;
  for (int s = 0; s < NSD; s++) {
    float f = __expf(pmax[((size_t)(b * NSD + s)) * 64 + e] - gm);
    unsigned int v = pp[(size_t)s * slab + base];
    a0 += f * bf2f((unsigned short)(v & 0xffff));
    a1 += f * bf2f((unsigned short)(v >> 16));
  }
  int d = t * 2;
  xs_f[((size_t)e * D + d) * B + b]     = a0 * inv;
  xs_f[((size_t)e * D + d + 1) * B + b] = a1 * inv;
}

// ---- K4: gemm1, fill-shaped + nt loads. grid 512 = (e, dq 0..7), block 256 ----
__global__ __launch_bounds__(256) void k_g1(const float* __restrict__ w1,
                                            const float* __restrict__ xs_f,
                                            unsigned short* __restrict__ h_part) {
  __shared__ float xsm[64 * 8];  // 2 KB
  int blk = blockIdx.x;
  int dq = blk & 7, e = blk >> 3;
  int t = threadIdx.x;
  if (t < 128)
    ((float4*)xsm)[t] = ((const float4*)(xs_f + ((size_t)e * D + dq * 64) * B))[t];
  __syncthreads();
  const float* wp = w1 + ((size_t)e * D + dq * 64) * H + t * 8;
  float acc[8][8];
#pragma unroll
  for (int i = 0; i < 8; i++)
#pragma unroll
    for (int j = 0; j < 8; j++) acc[i][j] = 0.f;
#pragma unroll 4
  for (int r = 0; r < 64; r++) {
    f32x4 wa = ldnt4(wp + (size_t)r * H);
    f32x4 wb = ldnt4(wp + (size_t)r * H + 4);
    float x8[8];
    *(float4*)&x8[0] = *(float4*)&xsm[r * 8];
    *(float4*)&x8[4] = *(float4*)&xsm[r * 8 + 4];
#pragma unroll
    for (int bb = 0; bb < 8; bb++) {
      acc[0][bb] += wa[0] * x8[bb]; acc[1][bb] += wa[1] * x8[bb];
      acc[2][bb] += wa[2] * x8[bb]; acc[3][bb] += wa[3] * x8[bb];
      acc[4][bb] += wb[0] * x8[bb]; acc[5][bb] += wb[1] * x8[bb];
      acc[6][bb] += wb[2] * x8[bb]; acc[7][bb] += wb[3] * x8[bb];
    }
  }
  unsigned short* op = h_part + (((size_t)dq * E + e) * H + t * 8) * B;
#pragma unroll
  for (int i = 0; i < 8; i++) {
    unsigned short us[8];
#pragma unroll
    for (int j = 0; j < 8; j++) us[j] = f2bf(acc[i][j]);
    *(uint4*)(op + (size_t)i * 8) = *(uint4*)us;
  }
}

// ---- K5: gemm2, fill-shaped + gelu fold + nt + float4 kk-split.
// grid 512 = (e, kq 0..7), block 256; each kk-half sweeps 256 KB contiguous.
__global__ __launch_bounds__(256) void k_g2(const float* __restrict__ w2,
                                            const float* __restrict__ b1,
                                            const unsigned short* __restrict__ h_part,
                                            unsigned short* __restrict__ ys_part) {
  __shared__ float hsm[256 * 8];    // 8 KB
  __shared__ float cbuf[128 * 33];  // 16.9 KB (padded, conflict-free)
  int blk = blockIdx.x;
  int kq = blk & 7, e = blk >> 3;
  int t = threadIdx.x;
  {
    int j = kq * 256 + t;
    const unsigned short* base = h_part + ((size_t)e * H + j) * B;
    float a[8] = {0.f, 0.f, 0.f, 0.f, 0.f, 0.f, 0.f, 0.f};
#pragma unroll
    for (int dq = 0; dq < NQ1; dq++) {
      u32x4 v = ldntu4(base + (size_t)dq * E * H * B);
      const unsigned short* u = (const unsigned short*)&v;
#pragma unroll
      for (int bb = 0; bb < 8; bb++) a[bb] += bf2f(u[bb]);
    }
    float bias = b1[(size_t)e * H + j];
#pragma unroll
    for (int bb = 0; bb < 8; bb++) {
      float vv = a[bb] + bias;
      hsm[t * 8 + bb] = 0.5f * vv * (1.0f + erff(vv * 0.70710678118654752f));
    }
  }
  __syncthreads();
  int kk = t >> 7, dq2 = t & 127;
  int d0 = dq2 * 4;
  const float* wp = w2 + ((size_t)e * H + kq * 256 + kk * 128) * D + d0;
  const float* hb = hsm + kk * 128 * 8;
  float acc[4][8];
#pragma unroll
  for (int i = 0; i < 4; i++)
#pragma unroll
    for (int j = 0; j < 8; j++) acc[i][j] = 0.f;
#pragma unroll 4
  for (int r = 0; r < 128; r++) {
    f32x4 w = ldnt4(wp + (size_t)r * D);
    float h8[8];
    *(float4*)&h8[0] = *(float4*)&hb[r * 8];
    *(float4*)&h8[4] = *(float4*)&hb[r * 8 + 4];
#pragma unroll
    for (int bb = 0; bb < 8; bb++) {
      acc[0][bb] += w[0] * h8[bb]; acc[1][bb] += w[1] * h8[bb];
      acc[2][bb] += w[2] * h8[bb]; acc[3][bb] += w[3] * h8[bb];
    }
  }
  if (kk) {
    float* cb = &cbuf[dq2 * 33];
#pragma unroll
    for (int i = 0; i < 4; i++) {
      *(float4*)(cb + i * 8)     = *(float4*)&acc[i][0];
      *(float4*)(cb + i * 8 + 4) = *(float4*)&acc[i][4];
    }
  }
  __syncthreads();
  if (!kk) {
    const float* cb = &cbuf[dq2 * 33];
    unsigned short* op = ys_part + (((size_t)kq * E + e) * D + d0) * B;
#pragma unroll
    for (int i = 0; i < 4; i++) {
      unsigned short us[8];
#pragma unroll
      for (int j = 0; j < 8; j++)
        us[j] = f2bf(acc[i][j] + cb[i * 8 + j]);
      *(uint4*)(op + (size_t)i * 8) = *(uint4*)us;
    }
  }
}

// ---- K6: ysT[b][d][e] = bf16(sum_kq ys_part + b2). grid E*4=256 ----
__global__ __launch_bounds__(256) void k_ysred(const unsigned short* __restrict__ ys_part,
                                               const float* __restrict__ b2,
                                               unsigned short* __restrict__ ysT) {
  int e = blockIdx.x >> 2, kqq = blockIdx.x & 3;
  int t = threadIdx.x;
  int i4 = kqq * 256 + t;
  float a[4] = {0.f, 0.f, 0.f, 0.f};
  for (int ks = 0; ks < NQ2; ks++) {
    const unsigned short* q = ys_part + ((size_t)ks * E + e) * D * B;
    ushort4 v = *(const ushort4*)(q + (size_t)i4 * 4);
    a[0] += bf2f(v.x); a[1] += bf2f(v.y); a[2] += bf2f(v.z); a[3] += bf2f(v.w);
  }
  int d = i4 >> 1, bh = (i4 & 1) * 4;
  float bias = b2[e * D + d];
#pragma unroll
  for (int j = 0; j < 4; j++)
    ysT[((size_t)(bh + j) * D + d) * E + e] = f2bf(a[j] + bias);
}

// ---- K7: combine via MFMA (unchanged). grid B*64*2=1024 ----
__global__ __launch_bounds__(256) void k_combine(const unsigned short* __restrict__ logitsb,
                                                 const unsigned short* __restrict__ ysT,
                                                 float* __restrict__ y) {
  __shared__ unsigned int yss[256 * 34];
  __shared__ unsigned int cb[64 * 34];
  __shared__ float red[64][4];
  __shared__ float gmx[64], gsm[64];
  int t = threadIdx.x;
  int lane = t & 63, w = t >> 6;
  int blk = blockIdx.x;
  int dg = blk & 1, mb = (blk >> 1) & 63, b = blk >> 7;
  int m0 = mb * 64;
  {
    int dloc = t >> 3, ch = t & 7;
    const unsigned short* src = ysT + ((size_t)b * D + dg * 256) * E;
#pragma unroll
    for (int p = 0; p < 8; p++) {
      int d = p * 32 + dloc;
      const unsigned int* sp = (const unsigned int*)&src[(size_t)d * E + ch * 8];
      unsigned int* dst = &yss[d * 34 + ch * 4];
      dst[0] = sp[0]; dst[1] = sp[1]; dst[2] = sp[2]; dst[3] = sp[3];
    }
  }
  int row = t >> 2, sub = t & 3;
  float r16[16];
  {
    const unsigned short* Lr = logitsb + ((size_t)(b * M + m0 + row)) * E + sub * 16;
    short8v l0 = *(const short8v*)Lr;
    short8v l1 = *(const short8v*)(Lr + 8);
#pragma unroll
    for (int k = 0; k < 8; k++) {
      r16[k]     = bf2f((unsigned short)l0[k]);
      r16[8 + k] = bf2f((unsigned short)l1[k]);
    }
  }
  float lm = -1e30f;
#pragma unroll
  for (int k = 0; k < 16; k++) lm = fmaxf(lm, r16[k]);
  red[row][sub] = lm;
  __syncthreads();
  if (sub == 0)
    gmx[row] = fmaxf(fmaxf(red[row][0], red[row][1]), fmaxf(red[row][2], red[row][3]));
  __syncthreads();
  float g = gmx[row];
  float ls = 0.f;
#pragma unroll
  for (int k = 0; k < 16; k++) {
    r16[k] = __expf(r16[k] - g);
    ls += r16[k];
  }
  red[row][sub] = ls;
  __syncthreads();
  if (sub == 0)
    gsm[row] = 1.0f / (red[row][0] + red[row][1] + red[row][2] + red[row][3]);
  __syncthreads();
  float is = gsm[row];
  {
    unsigned int us[8];
#pragma unroll
    for (int k = 0; k < 8; k++)
      us[k] = (unsigned int)f2bf(r16[2 * k] * is) |
              ((unsigned int)f2bf(r16[2 * k + 1] * is) << 16);
    unsigned int* dst = &cb[row * 34 + sub * 8];
#pragma unroll
    for (int k = 0; k < 8; k++) dst[k] = us[k];
  }
  __syncthreads();
  int kg = lane >> 4, l15 = lane & 15;
  f32x4 acc[4][4];
#pragma unroll
  for (int i = 0; i < 4; i++)
#pragma unroll
    for (int j = 0; j < 4; j++) acc[i][j] = (f32x4)(0.f);
#pragma unroll
  for (int ks = 0; ks < 2; ks++) {
    short8v afr[4];
#pragma unroll
    for (int mt = 0; mt < 4; mt++)
      afr[mt] = ld4w(cb, (mt * 16 + l15) * 34 + ks * 16 + kg * 4);
#pragma unroll
    for (int dt = 0; dt < 4; dt++) {
      short8v bfr = ld4w(yss, (w * 64 + dt * 16 + l15) * 34 + ks * 16 + kg * 4);
#pragma unroll
      for (int mt = 0; mt < 4; mt++)
        acc[mt][dt] = __builtin_amdgcn_mfma_f32_16x16x32_bf16(afr[mt], bfr, acc[mt][dt], 0, 0, 0);
    }
  }
#pragma unroll
  for (int mt = 0; mt < 4; mt++)
#pragma unroll
    for (int dt = 0; dt < 4; dt++)
#pragma unroll
      for (int r = 0; r < 4; r++) {
        int m = mt * 16 + kg * 4 + r;
        int d = dg * 256 + w * 64 + dt * 16 + l15;
        y[((size_t)(b * M + m0 + m)) * D + d] = acc[mt][dt][r];
      }
}

extern "C" void kernel_launch(void* const* d_in, const int* in_sizes, int n_in,
                              void* d_out, int out_size, void* d_ws, size_t ws_size,
                              hipStream_t stream) {
  const float* x     = (const float*)d_in[0];
  const float* phi   = (const float*)d_in[1];
  const float* scale = (const float*)d_in[2];
  const float* w1    = (const float*)d_in[3];
  const float* b1    = (const float*)d_in[4];
  const float* w2    = (const float*)d_in[5];
  const float* b2    = (const float*)d_in[6];
  float* y = (float*)d_out;
  float* ws = (float*)d_ws;
  (void)in_sizes; (void)n_in; (void)out_size; (void)ws_size;

  unsigned short* phT     = (unsigned short*)(ws + OFF_PHT);
  unsigned short* xnb     = (unsigned short*)(ws + OFF_XNB);
  unsigned short* logitsb = (unsigned short*)(ws + OFF_LOGB);
  float* pmax    = ws + OFF_PMAX;
  float* psum    = ws + OFF_PSUM;
  unsigned short* xs_part = (unsigned short*)(ws + OFF_XSP);
  float* xs_f    = ws + OFF_XSF;
  unsigned short* ysT     = (unsigned short*)(ws + OFF_YST);
  unsigned short* h_part  = xnb;      // alias (lifetimes disjoint)
  unsigned short* ys_part = xs_part;  // alias (lifetimes disjoint)

  k_phinorm<<<E, 256, 0, stream>>>(phi, scale, phT);
  k_logdis<<<B * NSD, 256, 0, stream>>>(x, phT, xnb, logitsb, pmax, psum, xs_part);
  k_xsred<<<B * E, 256, 0, stream>>>(xs_part, pmax, psum, xs_f);
  k_g1<<<E * NQ1, 256, 0, stream>>>(w1, xs_f, h_part);
  k_g2<<<E * NQ2, 256, 0, stream>>>(w2, b1, h_part, ys_part);
  k_ysred<<<E * 4, 256, 0, stream>>>(ys_part, b2, ysT);
  k_combine<<<B * 64 * 2, 256, 0, stream>>>(logitsb, ysT, y);
}

// Round 15
// 166.031 us; speedup vs baseline: 1.1800x; 1.0715x over previous
//
#include <hip/hip_runtime.h>
#include <hip/hip_bf16.h>
#include <math.h>

// Soft-MoE forward. B=8, M=4096, D=512, E=64, P=1, H=2048.
// R15 = R12 (empirical best, 166.5us): fill-shaped MLP streams with
// nontemporal loads ONLY on read-once weight/h_part streams; normal
// cached loads/stores everywhere else (intermediates stay L3-resident).

namespace {
constexpr int B = 8, M = 4096, D = 512, E = 64, H = 2048;
constexpr int NSD = 32;   // 128-row m-splits
constexpr int NQ1 = 8;    // g1 d-slabs
constexpr int NQ2 = 8;    // g2 k-slabs

constexpr size_t OFF_PHT  = 0;                                   // D*E bf16
constexpr size_t OFF_XNB  = OFF_PHT  + (size_t)D * E / 2;        // B*M*D bf16 (aliased by h_part)
constexpr size_t OFF_LOGB = OFF_XNB  + (size_t)B * M * D / 2;    // B*M*E bf16
constexpr size_t OFF_PMAX = OFF_LOGB + (size_t)B * M * E / 2;    // B*NSD*E f32
constexpr size_t OFF_PSUM = OFF_PMAX + (size_t)B * NSD * E;
constexpr size_t OFF_XSP  = OFF_PSUM + (size_t)B * NSD * E;      // NSD*B*E*D bf16 (aliased by ys_part)
constexpr size_t OFF_XSF  = OFF_XSP  + (size_t)NSD * B * E * D / 2; // E*D*B f32
constexpr size_t OFF_YST  = OFF_XSF  + (size_t)E * D * B;        // B*D*E bf16
constexpr size_t WS_FLOATS = OFF_YST + (size_t)B * D * E / 2;    // ~57 MB
} // namespace

typedef __attribute__((ext_vector_type(8))) short short8v;
typedef __attribute__((ext_vector_type(4))) float f32x4;
typedef __attribute__((ext_vector_type(4))) unsigned int u32x4;

static __device__ inline unsigned short f2bf(float f) {
  __hip_bfloat16 h = __float2bfloat16(f);
  return *reinterpret_cast<unsigned short*>(&h);
}
static __device__ inline float bf2f(unsigned short u) {
  unsigned int x = ((unsigned int)u) << 16;
  return __uint_as_float(x);
}
static __device__ inline short8v ld4w(const unsigned int* p, int a) {
  union { unsigned int u[4]; short8v v; } x;
  x.u[0] = p[a]; x.u[1] = p[a + 1]; x.u[2] = p[a + 2]; x.u[3] = p[a + 3];
  return x.v;
}
static __device__ inline f32x4 ldnt4(const float* p) {
  return __builtin_nontemporal_load((const f32x4*)p);
}
static __device__ inline u32x4 ldntu4(const unsigned short* p) {
  return __builtin_nontemporal_load((const u32x4*)p);
}

// ---- K1: phT[e][d] = bf16(scale * l2norm(phi, axis=0)). grid 64, block 256 ----
__global__ __launch_bounds__(256) void k_phinorm(const float* __restrict__ phi,
                                                 const float* __restrict__ scale,
                                                 unsigned short* __restrict__ phT) {
  int e = blockIdx.x;
  int t = threadIdx.x;
  float v0 = phi[(size_t)t * E + e];
  float v1 = phi[(size_t)(t + 256) * E + e];
  __shared__ float red[256];
  red[t] = v0 * v0 + v1 * v1;
  __syncthreads();
  for (int s = 128; s; s >>= 1) {
    if (t < s) red[t] += red[t + s];
    __syncthreads();
  }
  float inv = scale[0] / fmaxf(sqrtf(red[0]), 1e-12f);
  phT[(size_t)e * D + t]       = f2bf(v0 * inv);
  phT[(size_t)e * D + t + 256] = f2bf(v1 * inv);
}

// ---- K2: fused rownorm + logits MFMA + stats + dispatch MFMA ----
__global__ __launch_bounds__(256) void k_logdis(const float* __restrict__ x,
                                                const unsigned short* __restrict__ phT,
                                                unsigned short* __restrict__ xnb,
                                                unsigned short* __restrict__ logitsb,
                                                float* __restrict__ pmax,
                                                float* __restrict__ psum,
                                                unsigned short* __restrict__ xs_part) {
  __shared__ __align__(16) unsigned char pool[80896];
  unsigned short* phs = (unsigned short*)pool;            // [64 e][520 k]
  unsigned short* xA  = (unsigned short*)(pool + 66560);  // [128 m][56 k]
  unsigned int* weT = (unsigned int*)pool;                // [64 e][65 mp]
  unsigned int* xnT = (unsigned int*)(pool + 16640);      // [128 d][65 mp]
  unsigned short* rp = (unsigned short*)(pool + 49920);   // [64 e][136 d]
  __shared__ float invs[128];
  __shared__ float smax[4][64];
  __shared__ float bmax[64];
  int t = threadIdx.x;
  int lane = t & 63, w = t >> 6;
  int blk = blockIdx.x;
  int b = blk >> 5, ms = blk & 31;
  int rowbase = blk * 128;
  {
    int e = t >> 2, q0 = (t & 3) * 16;
#pragma unroll
    for (int q = 0; q < 16; q++)
      *(short8v*)&phs[e * 520 + (q0 + q) * 8] =
          *(const short8v*)&phT[(size_t)e * D + (q0 + q) * 8];
  }
  int srow = t >> 1;
  int kb = (t & 1) * 16;
  float ss = 0.f;
  f32x4 acc[2][4];
#pragma unroll
  for (int i = 0; i < 2; i++)
#pragma unroll
    for (int j = 0; j < 4; j++) acc[i][j] = (f32x4)(0.f);
  int kg = lane >> 4;
  int l15 = lane & 15;
  for (int ks = 0; ks < 16; ks++) {
    __syncthreads();
    const float4* xp = (const float4*)(x + (size_t)(rowbase + srow) * D + ks * 32 + kb);
#pragma unroll
    for (int q = 0; q < 4; q++) {
      float4 v = xp[q];
      ss += v.x * v.x + v.y * v.y + v.z * v.z + v.w * v.w;
      ushort4 u;
      u.x = f2bf(v.x); u.y = f2bf(v.y); u.z = f2bf(v.z); u.w = f2bf(v.w);
      *(ushort4*)&xA[srow * 56 + kb + q * 4] = u;
    }
    __syncthreads();
    {
      uint4 x0 = *(uint4*)&xA[srow * 56 + kb];
      uint4 x1 = *(uint4*)&xA[srow * 56 + kb + 8];
      size_t go = (size_t)(rowbase + srow) * D + ks * 32 + kb;
      *(uint4*)&xnb[go]     = x0;
      *(uint4*)&xnb[go + 8] = x1;
    }
    short8v a0 = *(short8v*)&xA[(w * 32 + l15) * 56 + kg * 8];
    short8v a1 = *(short8v*)&xA[(w * 32 + 16 + l15) * 56 + kg * 8];
    short8v b0 = *(short8v*)&phs[(l15)      * 520 + ks * 32 + kg * 8];
    short8v b1 = *(short8v*)&phs[(16 + l15) * 520 + ks * 32 + kg * 8];
    short8v b2 = *(short8v*)&phs[(32 + l15) * 520 + ks * 32 + kg * 8];
    short8v b3 = *(short8v*)&phs[(48 + l15) * 520 + ks * 32 + kg * 8];
    acc[0][0] = __builtin_amdgcn_mfma_f32_16x16x32_bf16(a0, b0, acc[0][0], 0, 0, 0);
    acc[0][1] = __builtin_amdgcn_mfma_f32_16x16x32_bf16(a0, b1, acc[0][1], 0, 0, 0);
    acc[0][2] = __builtin_amdgcn_mfma_f32_16x16x32_bf16(a0, b2, acc[0][2], 0, 0, 0);
    acc[0][3] = __builtin_amdgcn_mfma_f32_16x16x32_bf16(a0, b3, acc[0][3], 0, 0, 0);
    acc[1][0] = __builtin_amdgcn_mfma_f32_16x16x32_bf16(a1, b0, acc[1][0], 0, 0, 0);
    acc[1][1] = __builtin_amdgcn_mfma_f32_16x16x32_bf16(a1, b1, acc[1][1], 0, 0, 0);
    acc[1][2] = __builtin_amdgcn_mfma_f32_16x16x32_bf16(a1, b2, acc[1][2], 0, 0, 0);
    acc[1][3] = __builtin_amdgcn_mfma_f32_16x16x32_bf16(a1, b3, acc[1][3], 0, 0, 0);
  }
  ss += __shfl_xor(ss, 1, 64);
  float iv = 1.0f / fmaxf(sqrtf(ss), 1e-12f);
  if ((t & 1) == 0) invs[srow] = iv;
  __syncthreads();
  int rsub = kg * 4;
  float lm[4] = {-1e30f, -1e30f, -1e30f, -1e30f};
#pragma unroll
  for (int fi = 0; fi < 2; fi++)
#pragma unroll
    for (int r = 0; r < 4; r++) {
      int row = w * 32 + fi * 16 + rsub + r;
      float ivr = invs[row];
#pragma unroll
      for (int eg = 0; eg < 4; eg++) {
        float v = acc[fi][eg][r] * ivr;
        logitsb[(size_t)(rowbase + row) * E + eg * 16 + l15] = f2bf(v);
        lm[eg] = fmaxf(lm[eg], v);
      }
    }
#pragma unroll
  for (int eg = 0; eg < 4; eg++) {
    lm[eg] = fmaxf(lm[eg], __shfl_xor(lm[eg], 16, 64));
    lm[eg] = fmaxf(lm[eg], __shfl_xor(lm[eg], 32, 64));
  }
  if (lane < 16)
#pragma unroll
    for (int eg = 0; eg < 4; eg++) smax[w][eg * 16 + lane] = lm[eg];
  __syncthreads();
  if (t < 64)
    bmax[t] = fmaxf(fmaxf(smax[0][t], smax[1][t]), fmaxf(smax[2][t], smax[3][t]));
  __syncthreads();
  float ps[4] = {0.f, 0.f, 0.f, 0.f};
#pragma unroll
  for (int fi = 0; fi < 2; fi++)
#pragma unroll
    for (int r2 = 0; r2 < 2; r2++) {
      int rowA = w * 32 + fi * 16 + rsub + 2 * r2;
      float iv0 = invs[rowA], iv1 = invs[rowA + 1];
#pragma unroll
      for (int eg = 0; eg < 4; eg++) {
        float bm = bmax[eg * 16 + l15];
        float p0 = __expf(acc[fi][eg][2 * r2]     * iv0 - bm);
        float p1 = __expf(acc[fi][eg][2 * r2 + 1] * iv1 - bm);
        ps[eg] += p0 + p1;
        weT[(eg * 16 + l15) * 65 + (w * 16 + fi * 8 + (rsub >> 1) + r2)] =
            (unsigned int)f2bf(p0 * iv0) | ((unsigned int)f2bf(p1 * iv1) << 16);
      }
    }
#pragma unroll
  for (int eg = 0; eg < 4; eg++) {
    ps[eg] += __shfl_xor(ps[eg], 16, 64);
    ps[eg] += __shfl_xor(ps[eg], 32, 64);
  }
  __syncthreads();
  if (lane < 16)
#pragma unroll
    for (int eg = 0; eg < 4; eg++) smax[w][eg * 16 + lane] = ps[eg];
  __syncthreads();
  if (t < 64) {
    pmax[(size_t)blk * 64 + t] = bmax[t];
    psum[(size_t)blk * 64 + t] =
        smax[0][t] + smax[1][t] + smax[2][t] + smax[3][t];
  }
  unsigned short* outp = xs_part + ((size_t)ms * B + b) * E * D;
  for (int dc = 0; dc < 4; dc++) {
    __syncthreads();
#pragma unroll
    for (int i = 0; i < 16; i++) {
      int flat = i * 256 + t;
      int mp = flat >> 6, d2 = flat & 63;
      size_t rbase = (size_t)(rowbase + 2 * mp) * D + dc * 128 + d2 * 2;
      unsigned int ua = *(const unsigned int*)&xnb[rbase];
      unsigned int ub = *(const unsigned int*)&xnb[rbase + D];
      xnT[(2 * d2 + 0) * 65 + mp] = (ua & 0xffffu) | ((ub & 0xffffu) << 16);
      xnT[(2 * d2 + 1) * 65 + mp] = (ua >> 16) | (ub & 0xffff0000u);
    }
    __syncthreads();
    f32x4 ac3[4][2];
#pragma unroll
    for (int i = 0; i < 4; i++) { ac3[i][0] = (f32x4)(0.f); ac3[i][1] = (f32x4)(0.f); }
#pragma unroll
    for (int ks2 = 0; ks2 < 4; ks2++) {
      short8v afr[4];
#pragma unroll
      for (int et = 0; et < 4; et++)
        afr[et] = ld4w(weT, (et * 16 + l15) * 65 + ks2 * 16 + kg * 4);
#pragma unroll
      for (int dtl = 0; dtl < 2; dtl++) {
        short8v bfr = ld4w(xnT, (w * 32 + dtl * 16 + l15) * 65 + ks2 * 16 + kg * 4);
#pragma unroll
        for (int et = 0; et < 4; et++)
          ac3[et][dtl] = __builtin_amdgcn_mfma_f32_16x16x32_bf16(afr[et], bfr, ac3[et][dtl], 0, 0, 0);
      }
    }
#pragma unroll
    for (int et = 0; et < 4; et++)
#pragma unroll
      for (int dtl = 0; dtl < 2; dtl++)
#pragma unroll
        for (int r = 0; r < 4; r++) {
          int e = et * 16 + rsub + r;
          int d = w * 32 + dtl * 16 + l15;
          rp[e * 136 + d] = f2bf(ac3[et][dtl][r]);
        }
    __syncthreads();
    {
      int g = t >> 4, dch = t & 15;
#pragma unroll
      for (int pp = 0; pp < 4; pp++) {
        int el = pp * 16 + g;
        uint4 v = *(uint4*)&rp[el * 136 + dch * 8];
        *(uint4*)(outp + (size_t)el * D + dc * 128 + dch * 8) = v;
      }
    }
  }
}

// ---- K3: xs_f[e][d][b] = (sum_ms xs_part * exp(pmax-gm)) / dsum. grid B*E=512 ----
__global__ __launch_bounds__(256) void k_xsred(const unsigned short* __restrict__ xs_part,
                                               const float* __restrict__ pmax,
                                               const float* __restrict__ psum,
                                               float* __restrict__ xs_f) {
  int blk = blockIdx.x;
  int b = blk >> 6, e = blk & 63;
  int t = threadIdx.x;
  float gm = -1e30f;
  for (int s = 0; s < NSD; s++)
    gm = fmaxf(gm, pmax[((size_t)(b * NSD + s)) * 64 + e]);
  float gs = 0.f;
  for (int s = 0; s < NSD; s++)
    gs += psum[((size_t)(b * NSD + s)) * 64 + e] *
          __expf(pmax[((size_t)(b * NSD + s)) * 64 + e] - gm);
  float inv = 1.0f / gs;
  size_t base = (((size_t)b * E + e) * D) / 2 + t;
  size_t slab = ((size_t)B * E * D) / 2;
  float a0 = 0.f, a1 = 0.f;
  const unsigned int* pp = (const unsigned int*)xs_part;
  for (int s = 0; s < NSD; s++) {
    float f = __expf(pmax[((size_t)(b * NSD + s)) * 64 + e] - gm);
    unsigned int v = pp[(size_t)s * slab + base];
    a0 += f * bf2f((unsigned short)(v & 0xffff));
    a1 += f * bf2f((unsigned short)(v >> 16));
  }
  int d = t * 2;
  xs_f[((size_t)e * D + d) * B + b]     = a0 * inv;
  xs_f[((size_t)e * D + d + 1) * B + b] = a1 * inv;
}

// ---- K4: gemm1, fill-shaped + nt loads. grid 512 = (e, dq 0..7), block 256 ----
__global__ __launch_bounds__(256) void k_g1(const float* __restrict__ w1,
                                            const float* __restrict__ xs_f,
                                            unsigned short* __restrict__ h_part) {
  __shared__ float xsm[64 * 8];  // 2 KB
  int blk = blockIdx.x;
  int dq = blk & 7, e = blk >> 3;
  int t = threadIdx.x;
  if (t < 128)
    ((float4*)xsm)[t] = ((const float4*)(xs_f + ((size_t)e * D + dq * 64) * B))[t];
  __syncthreads();
  const float* wp = w1 + ((size_t)e * D + dq * 64) * H + t * 8;
  float acc[8][8];
#pragma unroll
  for (int i = 0; i < 8; i++)
#pragma unroll
    for (int j = 0; j < 8; j++) acc[i][j] = 0.f;
#pragma unroll 4
  for (int r = 0; r < 64; r++) {
    f32x4 wa = ldnt4(wp + (size_t)r * H);
    f32x4 wb = ldnt4(wp + (size_t)r * H + 4);
    float x8[8];
    *(float4*)&x8[0] = *(float4*)&xsm[r * 8];
    *(float4*)&x8[4] = *(float4*)&xsm[r * 8 + 4];
#pragma unroll
    for (int bb = 0; bb < 8; bb++) {
      acc[0][bb] += wa[0] * x8[bb]; acc[1][bb] += wa[1] * x8[bb];
      acc[2][bb] += wa[2] * x8[bb]; acc[3][bb] += wa[3] * x8[bb];
      acc[4][bb] += wb[0] * x8[bb]; acc[5][bb] += wb[1] * x8[bb];
      acc[6][bb] += wb[2] * x8[bb]; acc[7][bb] += wb[3] * x8[bb];
    }
  }
  unsigned short* op = h_part + (((size_t)dq * E + e) * H + t * 8) * B;
#pragma unroll
  for (int i = 0; i < 8; i++) {
    unsigned short us[8];
#pragma unroll
    for (int j = 0; j < 8; j++) us[j] = f2bf(acc[i][j]);
    *(uint4*)(op + (size_t)i * 8) = *(uint4*)us;
  }
}

// ---- K5: gemm2, fill-shaped + gelu fold + nt + float4 kk-split.
// grid 512 = (e, kq 0..7), block 256; each kk-half sweeps 256 KB contiguous.
__global__ __launch_bounds__(256) void k_g2(const float* __restrict__ w2,
                                            const float* __restrict__ b1,
                                            const unsigned short* __restrict__ h_part,
                                            unsigned short* __restrict__ ys_part) {
  __shared__ float hsm[256 * 8];    // 8 KB
  __shared__ float cbuf[128 * 33];  // 16.9 KB (padded, conflict-free)
  int blk = blockIdx.x;
  int kq = blk & 7, e = blk >> 3;
  int t = threadIdx.x;
  {
    int j = kq * 256 + t;
    const unsigned short* base = h_part + ((size_t)e * H + j) * B;
    float a[8] = {0.f, 0.f, 0.f, 0.f, 0.f, 0.f, 0.f, 0.f};
#pragma unroll
    for (int dq = 0; dq < NQ1; dq++) {
      u32x4 v = ldntu4(base + (size_t)dq * E * H * B);
      const unsigned short* u = (const unsigned short*)&v;
#pragma unroll
      for (int bb = 0; bb < 8; bb++) a[bb] += bf2f(u[bb]);
    }
    float bias = b1[(size_t)e * H + j];
#pragma unroll
    for (int bb = 0; bb < 8; bb++) {
      float vv = a[bb] + bias;
      hsm[t * 8 + bb] = 0.5f * vv * (1.0f + erff(vv * 0.70710678118654752f));
    }
  }
  __syncthreads();
  int kk = t >> 7, dq2 = t & 127;
  int d0 = dq2 * 4;
  const float* wp = w2 + ((size_t)e * H + kq * 256 + kk * 128) * D + d0;
  const float* hb = hsm + kk * 128 * 8;
  float acc[4][8];
#pragma unroll
  for (int i = 0; i < 4; i++)
#pragma unroll
    for (int j = 0; j < 8; j++) acc[i][j] = 0.f;
#pragma unroll 4
  for (int r = 0; r < 128; r++) {
    f32x4 w = ldnt4(wp + (size_t)r * D);
    float h8[8];
    *(float4*)&h8[0] = *(float4*)&hb[r * 8];
    *(float4*)&h8[4] = *(float4*)&hb[r * 8 + 4];
#pragma unroll
    for (int bb = 0; bb < 8; bb++) {
      acc[0][bb] += w[0] * h8[bb]; acc[1][bb] += w[1] * h8[bb];
      acc[2][bb] += w[2] * h8[bb]; acc[3][bb] += w[3] * h8[bb];
    }
  }
  if (kk) {
    float* cb = &cbuf[dq2 * 33];
#pragma unroll
    for (int i = 0; i < 4; i++) {
      *(float4*)(cb + i * 8)     = *(float4*)&acc[i][0];
      *(float4*)(cb + i * 8 + 4) = *(float4*)&acc[i][4];
    }
  }
  __syncthreads();
  if (!kk) {
    const float* cb = &cbuf[dq2 * 33];
    unsigned short* op = ys_part + (((size_t)kq * E + e) * D + d0) * B;
#pragma unroll
    for (int i = 0; i < 4; i++) {
      unsigned short us[8];
#pragma unroll
      for (int j = 0; j < 8; j++)
        us[j] = f2bf(acc[i][j] + cb[i * 8 + j]);
      *(uint4*)(op + (size_t)i * 8) = *(uint4*)us;
    }
  }
}

// ---- K6: ysT[b][d][e] = bf16(sum_kq ys_part + b2). grid E*4=256 ----
__global__ __launch_bounds__(256) void k_ysred(const unsigned short* __restrict__ ys_part,
                                               const float* __restrict__ b2,
                                               unsigned short* __restrict__ ysT) {
  int e = blockIdx.x >> 2, kqq = blockIdx.x & 3;
  int t = threadIdx.x;
  int i4 = kqq * 256 + t;
  float a[4] = {0.f, 0.f, 0.f, 0.f};
  for (int ks = 0; ks < NQ2; ks++) {
    const unsigned short* q = ys_part + ((size_t)ks * E + e) * D * B;
    ushort4 v = *(const ushort4*)(q + (size_t)i4 * 4);
    a[0] += bf2f(v.x); a[1] += bf2f(v.y); a[2] += bf2f(v.z); a[3] += bf2f(v.w);
  }
  int d = i4 >> 1, bh = (i4 & 1) * 4;
  float bias = b2[e * D + d];
#pragma unroll
  for (int j = 0; j < 4; j++)
    ysT[((size_t)(bh + j) * D + d) * E + e] = f2bf(a[j] + bias);
}

// ---- K7: combine via MFMA. grid B*64*2=1024 ----
__global__ __launch_bounds__(256) void k_combine(const unsigned short* __restrict__ logitsb,
                                                 const unsigned short* __restrict__ ysT,
                                                 float* __restrict__ y) {
  __shared__ unsigned int yss[256 * 34];
  __shared__ unsigned int cb[64 * 34];
  __shared__ float red[64][4];
  __shared__ float gmx[64], gsm[64];
  int t = threadIdx.x;
  int lane = t & 63, w = t >> 6;
  int blk = blockIdx.x;
  int dg = blk & 1, mb = (blk >> 1) & 63, b = blk >> 7;
  int m0 = mb * 64;
  {
    int dloc = t >> 3, ch = t & 7;
    const unsigned short* src = ysT + ((size_t)b * D + dg * 256) * E;
#pragma unroll
    for (int p = 0; p < 8; p++) {
      int d = p * 32 + dloc;
      const unsigned int* sp = (const unsigned int*)&src[(size_t)d * E + ch * 8];
      unsigned int* dst = &yss[d * 34 + ch * 4];
      dst[0] = sp[0]; dst[1] = sp[1]; dst[2] = sp[2]; dst[3] = sp[3];
    }
  }
  int row = t >> 2, sub = t & 3;
  float r16[16];
  {
    const unsigned short* Lr = logitsb + ((size_t)(b * M + m0 + row)) * E + sub * 16;
    short8v l0 = *(const short8v*)Lr;
    short8v l1 = *(const short8v*)(Lr + 8);
#pragma unroll
    for (int k = 0; k < 8; k++) {
      r16[k]     = bf2f((unsigned short)l0[k]);
      r16[8 + k] = bf2f((unsigned short)l1[k]);
    }
  }
  float lm = -1e30f;
#pragma unroll
  for (int k = 0; k < 16; k++) lm = fmaxf(lm, r16[k]);
  red[row][sub] = lm;
  __syncthreads();
  if (sub == 0)
    gmx[row] = fmaxf(fmaxf(red[row][0], red[row][1]), fmaxf(red[row][2], red[row][3]));
  __syncthreads();
  float g = gmx[row];
  float ls = 0.f;
#pragma unroll
  for (int k = 0; k < 16; k++) {
    r16[k] = __expf(r16[k] - g);
    ls += r16[k];
  }
  red[row][sub] = ls;
  __syncthreads();
  if (sub == 0)
    gsm[row] = 1.0f / (red[row][0] + red[row][1] + red[row][2] + red[row][3]);
  __syncthreads();
  float is = gsm[row];
  {
    unsigned int us[8];
#pragma unroll
    for (int k = 0; k < 8; k++)
      us[k] = (unsigned int)f2bf(r16[2 * k] * is) |
              ((unsigned int)f2bf(r16[2 * k + 1] * is) << 16);
    unsigned int* dst = &cb[row * 34 + sub * 8];
#pragma unroll
    for (int k = 0; k < 8; k++) dst[k] = us[k];
  }
  __syncthreads();
  int kg = lane >> 4, l15 = lane & 15;
  f32x4 acc[4][4];
#pragma unroll
  for (int i = 0; i < 4; i++)
#pragma unroll
    for (int j = 0; j < 4; j++) acc[i][j] = (f32x4)(0.f);
#pragma unroll
  for (int ks = 0; ks < 2; ks++) {
    short8v afr[4];
#pragma unroll
    for (int mt = 0; mt < 4; mt++)
      afr[mt] = ld4w(cb, (mt * 16 + l15) * 34 + ks * 16 + kg * 4);
#pragma unroll
    for (int dt = 0; dt < 4; dt++) {
      short8v bfr = ld4w(yss, (w * 64 + dt * 16 + l15) * 34 + ks * 16 + kg * 4);
#pragma unroll
      for (int mt = 0; mt < 4; mt++)
        acc[mt][dt] = __builtin_amdgcn_mfma_f32_16x16x32_bf16(afr[mt], bfr, acc[mt][dt], 0, 0, 0);
    }
  }
#pragma unroll
  for (int mt = 0; mt < 4; mt++)
#pragma unroll
    for (int dt = 0; dt < 4; dt++)
#pragma unroll
      for (int r = 0; r < 4; r++) {
        int m = mt * 16 + kg * 4 + r;
        int d = dg * 256 + w * 64 + dt * 16 + l15;
        y[((size_t)(b * M + m0 + m)) * D + d] = acc[mt][dt][r];
      }
}

extern "C" void kernel_launch(void* const* d_in, const int* in_sizes, int n_in,
                              void* d_out, int out_size, void* d_ws, size_t ws_size,
                              hipStream_t stream) {
  const float* x     = (const float*)d_in[0];
  const float* phi   = (const float*)d_in[1];
  const float* scale = (const float*)d_in[2];
  const float* w1    = (const float*)d_in[3];
  const float* b1    = (const float*)d_in[4];
  const float* w2    = (const float*)d_in[5];
  const float* b2    = (const float*)d_in[6];
  float* y = (float*)d_out;
  float* ws = (float*)d_ws;
  (void)in_sizes; (void)n_in; (void)out_size; (void)ws_size;

  unsigned short* phT     = (unsigned short*)(ws + OFF_PHT);
  unsigned short* xnb     = (unsigned short*)(ws + OFF_XNB);
  unsigned short* logitsb = (unsigned short*)(ws + OFF_LOGB);
  float* pmax    = ws + OFF_PMAX;
  float* psum    = ws + OFF_PSUM;
  unsigned short* xs_part = (unsigned short*)(ws + OFF_XSP);
  float* xs_f    = ws + OFF_XSF;
  unsigned short* ysT     = (unsigned short*)(ws + OFF_YST);
  unsigned short* h_part  = xnb;      // alias (lifetimes disjoint)
  unsigned short* ys_part = xs_part;  // alias (lifetimes disjoint)

  k_phinorm<<<E, 256, 0, stream>>>(phi, scale, phT);
  k_logdis<<<B * NSD, 256, 0, stream>>>(x, phT, xnb, logitsb, pmax, psum, xs_part);
  k_xsred<<<B * E, 256, 0, stream>>>(xs_part, pmax, psum, xs_f);
  k_g1<<<E * NQ1, 256, 0, stream>>>(w1, xs_f, h_part);
  k_g2<<<E * NQ2, 256, 0, stream>>>(w2, b1, h_part, ys_part);
  k_ysred<<<E * 4, 256, 0, stream>>>(ys_part, b2, ysT);
  k_combine<<<B * 64 * 2, 256, 0, stream>>>(logitsb, ysT, y);
}